// Round 1
// baseline (238.298 us; speedup 1.0000x reference)
//
#include <hip/hip_runtime.h>

#define BB 64
#define CC 128
#define TT 4096
#define NN 6            // KNOT + 2
#define HH 819.0f       // (T-1)/(KNOT+1) = 4095/5, exact

// LDS swizzle for xp: stride-16 writes would hit only 2 banks (32-way
// conflict); +j/32 padding spreads them across all 32 banks (2-way, free).
__device__ __forceinline__ int padi(int j) { return j + (j >> 5); }

__global__ __launch_bounds__(256) void timewarp_kernel(
    const float* __restrict__ x,
    const float* __restrict__ yy,
    const float* __restrict__ mask_rand,
    float* __restrict__ out)
{
    const int row = blockIdx.x;          // b*C + c
    const int b   = row / CC;
    const int c   = row % CC;
    const int tid = threadIdx.x;

    const float* xrow = x + (size_t)row * TT;
    float* orow       = out + (size_t)row * TT;

    // mask_rand >= 0.5 -> output = x (bit-exact copy), uniform per block
    if (!(mask_rand[b] < 0.5f)) {
        const float4* xi = (const float4*)xrow;
        float4* oo = (float4*)orow;
        #pragma unroll
        for (int k = 0; k < 4; ++k) {
            int i = tid + 256 * k;
            oo[i] = xi[i];
        }
        return;
    }

    __shared__ float sh_fp[TT];                // x row
    __shared__ float sh_xp[TT + TT / 32];      // warped time, swizzled
    __shared__ float sh_part[256];
    __shared__ float sh_M[NN];
    __shared__ float sh_y[NN];

    // stage x row into LDS (coalesced float4)
    {
        const float4* xi = (const float4*)xrow;
        float4* fp4 = (float4*)sh_fp;
        #pragma unroll
        for (int k = 0; k < 4; ++k) {
            int i = tid + 256 * k;
            fp4[i] = xi[i];
        }
    }

    // thread 0: 6x6 not-a-knot solve (A constant; no-pivot elimination is
    // stable here: step 0 turns row1 into [0,819,0,...])
    if (tid == 0) {
        float y[NN];
        #pragma unroll
        for (int k = 0; k < NN; ++k)
            y[k] = yy[((size_t)b * NN + k) * CC + c];
        float Aug[NN][NN + 1];
        #pragma unroll
        for (int i = 0; i < NN; ++i)
            #pragma unroll
            for (int j = 0; j < NN + 1; ++j)
                Aug[i][j] = 0.0f;
        Aug[0][0] = 1.0f;  Aug[0][1] = -2.0f;  Aug[0][2] = 1.0f;
        Aug[5][3] = 1.0f;  Aug[5][4] = -2.0f;  Aug[5][5] = 1.0f;
        #pragma unroll
        for (int i = 1; i < NN - 1; ++i) {
            Aug[i][i - 1] = HH / 6.0f;          // 136.5
            Aug[i][i]     = 2.0f * HH / 3.0f;   // 546
            Aug[i][i + 1] = HH / 6.0f;
            Aug[i][NN]    = (y[i + 1] - 2.0f * y[i] + y[i - 1]) / HH;
        }
        #pragma unroll
        for (int k = 0; k < NN; ++k) {
            float inv = 1.0f / Aug[k][k];
            #pragma unroll
            for (int i = k + 1; i < NN; ++i) {
                float m = Aug[i][k] * inv;
                #pragma unroll
                for (int j = k; j < NN + 1; ++j)
                    Aug[i][j] -= m * Aug[k][j];
            }
        }
        float M[NN];
        #pragma unroll
        for (int i = NN - 1; i >= 0; --i) {
            float s = Aug[i][NN];
            #pragma unroll
            for (int j = i + 1; j < NN; ++j)
                s -= Aug[i][j] * M[j];
            M[i] = s / Aug[i][i];
        }
        #pragma unroll
        for (int k = 0; k < NN; ++k) { sh_M[k] = M[k]; sh_y[k] = y[k]; }
    }
    __syncthreads();

    // curve + local inclusive scan (16 contiguous t per thread)
    const float inv6h = 1.0f / (6.0f * HH);
    const float hd6   = HH / 6.0f;
    const float invh  = 1.0f / HH;

    float loc[16];
    float running = 0.0f;
    const int t0 = tid * 16;
    #pragma unroll
    for (int k = 0; k < 16; ++k) {
        int t = t0 + k;
        int idx = t / 819;                 // integer div == floor(t/h), h exact
        idx = idx > 4 ? 4 : idx;
        float xl  = (float)idx * HH;
        float ft  = (float)t;
        float dxl = ft - xl;
        float dxr = xl + HH - ft;
        float Mi  = sh_M[idx], Mi1 = sh_M[idx + 1];
        float yi  = sh_y[idx], yi1 = sh_y[idx + 1];
        float curve = (Mi * dxr * dxr * dxr + Mi1 * dxl * dxl * dxl) * inv6h
                    + (yi * invh - Mi * hd6) * dxr
                    + (yi1 * invh - Mi1 * hd6) * dxl;
        running += curve;
        loc[k] = running;
    }
    sh_part[tid] = running;
    __syncthreads();

    // Hillis-Steele inclusive scan over 256 partials
    #pragma unroll
    for (int off = 1; off < 256; off <<= 1) {
        float v = (tid >= off) ? sh_part[tid - off] : 0.0f;
        __syncthreads();
        sh_part[tid] += v;
        __syncthreads();
    }
    float total = sh_part[255];
    float offs  = sh_part[tid] - running;   // exclusive prefix
    float scale = 4095.0f / total;          // tt * (T-1) / tt_last
    #pragma unroll
    for (int k = 0; k < 16; ++k)
        sh_xp[padi(t0 + k)] = (loc[k] + offs) * scale;
    __syncthreads();

    // np.interp(0..T-1, xp, fp): binary search for first query, then
    // monotone two-pointer walk (queries and xp both increasing)
    float res[16];
    int j;
    {
        float q0 = (float)t0;
        int lo = -1, hi = TT;              // invariant: xp[lo] <= q0 < xp[hi]
        while (hi - lo > 1) {
            int mid = (lo + hi) >> 1;
            if (sh_xp[padi(mid)] <= q0) lo = mid; else hi = mid;
        }
        j = lo;                            // largest j with xp[j] <= q0 (or -1)
    }
    #pragma unroll
    for (int k = 0; k < 16; ++k) {
        float q = (float)(t0 + k);
        while (j < TT - 1 && sh_xp[padi(j + 1)] <= q) ++j;
        float r;
        if (j < 0)            r = sh_fp[0];        // q < xp[0]
        else if (j >= TT - 1) r = sh_fp[TT - 1];   // q >= xp[T-1]
        else {
            float x0 = sh_xp[padi(j)];
            float x1 = sh_xp[padi(j + 1)];
            float f0 = sh_fp[j];
            float f1 = sh_fp[j + 1];
            r = f0 + (q - x0) * (f1 - f0) / (x1 - x0);
        }
        res[k] = r;
    }

    // direct float4 stores; 4 stores/thread complete every cache line, so
    // L2 merges the 64B-strided lanes before HBM writeback
    float4* oo = (float4*)orow;
    #pragma unroll
    for (int k = 0; k < 4; ++k) {
        float4 v = make_float4(res[4*k], res[4*k+1], res[4*k+2], res[4*k+3]);
        oo[tid * 4 + k] = v;
    }
}

extern "C" void kernel_launch(void* const* d_in, const int* in_sizes, int n_in,
                              void* d_out, int out_size, void* d_ws, size_t ws_size,
                              hipStream_t stream) {
    const float* x    = (const float*)d_in[0];   // (64,128,4096) fp32
    const float* yy   = (const float*)d_in[1];   // (64,6,128)    fp32
    const float* mask = (const float*)d_in[2];   // (64,1,1)      fp32
    float* out = (float*)d_out;                  // (64,128,4096) fp32
    timewarp_kernel<<<dim3(BB * CC), dim3(256), 0, stream>>>(x, yy, mask, out);
}

// Round 2
// 237.330 us; speedup vs baseline: 1.0041x; 1.0041x over previous
//
#include <hip/hip_runtime.h>

#define BB 64
#define CC 128
#define TT 4096
#define NN 6            // KNOT + 2
#define HH 819.0f       // (T-1)/(KNOT+1) = 4095/5, exact

// LDS pad: +1 float per 32 breaks power-of-2 stride conflicts (2-way max = free)
__device__ __forceinline__ int padi(int j) { return j + (j >> 5); }

__global__ __launch_bounds__(256) void timewarp_kernel(
    const float* __restrict__ x,
    const float* __restrict__ yy,
    const float* __restrict__ mask_rand,
    float* __restrict__ out)
{
    const int row = blockIdx.x;          // b*C + c
    const int b   = row / CC;
    const int c   = row % CC;
    const int tid = threadIdx.x;

    const float* xrow = x + (size_t)row * TT;
    float* orow       = out + (size_t)row * TT;

    // mask_rand >= 0.5 -> bit-exact copy (uniform per block)
    if (!(mask_rand[b] < 0.5f)) {
        const float4* xi = (const float4*)xrow;
        float4* oo = (float4*)orow;
        #pragma unroll
        for (int k = 0; k < 4; ++k) {
            int i = tid + 256 * k;
            oo[i] = xi[i];
        }
        return;
    }

    __shared__ float sh_res[TT + TT / 32];   // scatter target, padded
    __shared__ float sh_wsum[4];             // per-wave scan totals
    __shared__ float sh_xf[256];             // neighbor-exchange: first xp
    __shared__ float sh_ff[256];             // neighbor-exchange: first fp

    // ---- 6x6 not-a-knot solve, redundantly on every thread ----
    // A is compile-time constant -> elimination multipliers fold to constants;
    // yy addresses are block-uniform -> scalar loads. No barrier needed.
    float Mv[NN];
    float y[NN];
    {
        #pragma unroll
        for (int k = 0; k < NN; ++k)
            y[k] = yy[((size_t)b * NN + k) * CC + c];
        float Aug[NN][NN + 1];
        #pragma unroll
        for (int i = 0; i < NN; ++i)
            #pragma unroll
            for (int j = 0; j < NN + 1; ++j)
                Aug[i][j] = 0.0f;
        Aug[0][0] = 1.0f;  Aug[0][1] = -2.0f;  Aug[0][2] = 1.0f;
        Aug[5][3] = 1.0f;  Aug[5][4] = -2.0f;  Aug[5][5] = 1.0f;
        #pragma unroll
        for (int i = 1; i < NN - 1; ++i) {
            Aug[i][i - 1] = HH / 6.0f;
            Aug[i][i]     = 2.0f * HH / 3.0f;
            Aug[i][i + 1] = HH / 6.0f;
            Aug[i][NN]    = (y[i + 1] - 2.0f * y[i] + y[i - 1]) / HH;
        }
        #pragma unroll
        for (int k = 0; k < NN; ++k) {
            float inv = 1.0f / Aug[k][k];
            #pragma unroll
            for (int i = k + 1; i < NN; ++i) {
                float m = Aug[i][k] * inv;
                #pragma unroll
                for (int j = k; j < NN + 1; ++j)
                    Aug[i][j] -= m * Aug[k][j];
            }
        }
        #pragma unroll
        for (int i = NN - 1; i >= 0; --i) {
            float s = Aug[i][NN];
            #pragma unroll
            for (int j = i + 1; j < NN; ++j)
                s -= Aug[i][j] * Mv[j];
            Mv[i] = s / Aug[i][i];
        }
    }

    // ---- load this thread's 16 fp values into registers ----
    const int t0 = tid * 16;
    float fpv[17];
    {
        const float4* xi = (const float4*)(xrow + t0);
        #pragma unroll
        for (int k = 0; k < 4; ++k) {
            float4 v = xi[k];
            fpv[4 * k + 0] = v.x; fpv[4 * k + 1] = v.y;
            fpv[4 * k + 2] = v.z; fpv[4 * k + 3] = v.w;
        }
    }

    // ---- curve + thread-local inclusive scan ----
    const float inv6h = 1.0f / (6.0f * HH);
    const float hd6   = HH / 6.0f;
    const float invh  = 1.0f / HH;
    float loc[16];
    float running = 0.0f;
    #pragma unroll
    for (int k = 0; k < 16; ++k) {
        int t = t0 + k;
        int idx = t / 819;               // == floor(t/h), h exact
        idx = idx > 4 ? 4 : idx;
        float xl  = (float)idx * HH;
        float ft  = (float)t;
        float dxl = ft - xl;
        float dxr = xl + HH - ft;
        float Mi  = Mv[idx], Mi1 = Mv[idx + 1];
        float yi  = y[idx],  yi1 = y[idx + 1];
        float curve = (Mi * dxr * dxr * dxr + Mi1 * dxl * dxl * dxl) * inv6h
                    + (yi * invh - Mi * hd6) * dxr
                    + (yi1 * invh - Mi1 * hd6) * dxl;
        running += curve;
        loc[k] = running;
    }

    // ---- wave scan (shfl, no barriers) + cross-wave fixup (1 barrier) ----
    const int lane = tid & 63, wid = tid >> 6;
    float ws = running;
    #pragma unroll
    for (int d = 1; d < 64; d <<= 1) {
        float v = __shfl_up(ws, d, 64);
        if (lane >= d) ws += v;
    }
    if (lane == 63) sh_wsum[wid] = ws;
    __syncthreads();
    float wo = 0.0f, total = 0.0f;
    #pragma unroll
    for (int w = 0; w < 4; ++w) {
        float s = sh_wsum[w];
        total += s;
        if (w < wid) wo += s;
    }
    const float offs  = wo + (ws - running);   // exclusive prefix of this thread
    const float scale = 4095.0f / total;       // tt * (T-1) / tt_last

    float xpv[17];
    #pragma unroll
    for (int k = 0; k < 16; ++k)
        xpv[k] = (loc[k] + offs) * scale;

    // neighbor exchange for the 17th boundary value
    sh_xf[tid] = xpv[0];
    sh_ff[tid] = fpv[0];
    __syncthreads();
    xpv[16] = (tid < 255) ? sh_xf[tid + 1] : xpv[15];  // tid 255: unused
    fpv[16] = (tid < 255) ? sh_ff[tid + 1] : fpv[15];

    // ---- forward scatter: segment j owns q in [ceil(xp[j]), ceil(xp[j+1])-1] ----
    // head: q < xp[0] -> fp[0]
    if (tid == 0) {
        int q1 = (int)ceilf(xpv[0]);
        if (q1 > TT) q1 = TT;
        for (int q = 0; q < q1; ++q) sh_res[padi(q)] = fpv[0];
    }
    const int nseg = (tid < 255) ? 16 : 15;    // segments 0..4094 total
    #pragma unroll
    for (int k = 0; k < 16; ++k) {
        if (k < nseg) {
            float xa = xpv[k],  xb = xpv[k + 1];
            float fa = fpv[k],  fb = fpv[k + 1];
            int qlo = (int)ceilf(xa);  if (qlo < 0) qlo = 0;
            int qhi = (int)ceilf(xb) - 1;  if (qhi > TT - 1) qhi = TT - 1;
            float d = xb - xa;
            float slope = (d > 0.0f) ? (fb - fa) / d : 0.0f;
            for (int q = qlo; q <= qhi; ++q)
                sh_res[padi(q)] = fa + ((float)q - xa) * slope;
        }
    }
    // tail: q >= xp[4095] -> fp[4095]
    if (tid == 255) {
        int q0 = (int)ceilf(xpv[15]);
        if (q0 < 0) q0 = 0;
        for (int q = q0; q <= TT - 1; ++q) sh_res[padi(q)] = fpv[15];
    }
    __syncthreads();

    // ---- restage: coalesced float4 stores ----
    // within a 32-float block, padded addresses stay contiguous, so
    // padi(base)+e is valid for e=0..3 when base%4==0
    float4* oo = (float4*)orow;
    #pragma unroll
    for (int kk = 0; kk < 4; ++kk) {
        int i4 = tid + 256 * kk;
        int fb = 4 * i4;
        int p  = padi(fb);
        float4 v;
        v.x = sh_res[p + 0];
        v.y = sh_res[p + 1];
        v.z = sh_res[p + 2];
        v.w = sh_res[p + 3];
        oo[i4] = v;
    }
}

extern "C" void kernel_launch(void* const* d_in, const int* in_sizes, int n_in,
                              void* d_out, int out_size, void* d_ws, size_t ws_size,
                              hipStream_t stream) {
    const float* x    = (const float*)d_in[0];   // (64,128,4096) fp32
    const float* yy   = (const float*)d_in[1];   // (64,6,128)    fp32
    const float* mask = (const float*)d_in[2];   // (64,1,1)      fp32
    float* out = (float*)d_out;                  // (64,128,4096) fp32
    timewarp_kernel<<<dim3(BB * CC), dim3(256), 0, stream>>>(x, yy, mask, out);
}